// Round 10
// baseline (517.777 us; speedup 1.0000x reference)
//
#include <hip/hip_runtime.h>
#include <hip/hip_bf16.h>

// MLA forward, MI355X/gfx950.
// B=4, S=2048, D_MODEL=1024, H=16, D_H=64, D_HR=32, D_LATENT=256, d_qk=96.
//
// R10: 5-dispatch pipeline. RoPE fused into GEMM epilogues via __shfl_xor(1)
// lane-pairing (rope pairs = adjacent columns = adjacent lanes; wave-uniform
// selection, fp32-domain rotation). gemm2+gemm_kv merged into one dispatch.
// flash_attn untouched (R4/R6/R9 version, measured 96.1/97.9/95.5us).

typedef __attribute__((ext_vector_type(8))) __bf16 bf16x8;
typedef __attribute__((ext_vector_type(4))) float f32x4;
typedef __attribute__((ext_vector_type(16))) float f32x16;
typedef __attribute__((ext_vector_type(4))) unsigned short us4;

#define DEV static __device__ __forceinline__

DEV unsigned short f2b(float f) {
  union { __hip_bfloat16 h; unsigned short u; } v;
  v.h = __float2bfloat16(f);
  return v.u;
}
DEV unsigned int f2b2(float lo, float hi) {   // packed 2xf32 -> 2xbf16
  union { __hip_bfloat162 h2; unsigned int u; } v;
  float2 t; t.x = lo; t.y = hi;
  v.h2 = __float22bfloat162_rn(t);
  return v.u;
}
DEV f32x4 mfma16(bf16x8 a, bf16x8 b, f32x4 c) {
  return __builtin_amdgcn_mfma_f32_16x16x32_bf16(a, b, c, 0, 0, 0);
}
DEV f32x16 mfma32(bf16x8 a, bf16x8 b, f32x16 c) {
  return __builtin_amdgcn_mfma_f32_32x32x16_bf16(a, b, c, 0, 0, 0);
}
DEV void load_lds16(const void* g, void* lds) {
  __builtin_amdgcn_global_load_lds((__attribute__((address_space(1))) void*)g,
                                   (__attribute__((address_space(3))) void*)lds,
                                   16, 0, 0);
}

// Q-side prescale folded into W_UQ^T / W_QR^T: (1/sqrt(96)) * log2(e).
#define KSC2f 0.14724444690f
// Clip bound in the scaled domain: 80 * KSC2.
#define CLIPf 11.7795557220f
// log2(10000)/16, for RoPE inv-freq in exp2 form.
#define RINVf 0.8304820237686285f

// ---------------- prep: convert x (fp32->bf16) + 8 weight transposes, ONE dispatch ----------
struct TWArgs { const float* W[8]; unsigned short* T[8]; };
__global__ __launch_bounds__(256) void prep(const float* __restrict__ x,
                                            unsigned short* __restrict__ xb, TWArgs a) {
  if (blockIdx.x < 8192) {
    long i = (long)(blockIdx.x * 256 + threadIdx.x) * 4;
    float4 v = *(const float4*)(x + i);
    us4 o = { f2b(v.x), f2b(v.y), f2b(v.z), f2b(v.w) };
    *(us4*)(xb + i) = o;
    return;
  }
  int bid = blockIdx.x - 8192;
  int g;
  if      (bid < 256)  g = 0;
  else if (bid < 512)  g = 1;
  else if (bid < 544)  g = 2;
  else if (bid < 800)  g = 3;
  else if (bid < 928)  g = 4;
  else if (bid < 1184) g = 5;
  else if (bid < 1440) g = 6;
  else                 g = 7;
  const int starts[8] = {0, 256, 512, 544, 800, 928, 1184, 1440};
  int local = bid - starts[g];
  int K = (g >= 3 && g <= 6) ? 256 : 1024;
  int N = (g < 2) ? 256 : (g == 2 ? 32 : (g == 4 ? 512 : 1024));
  int tilesX = N >> 5;
  int n0 = (local % tilesX) * 32, k0 = (local / tilesX) * 32;
  const float* W = a.W[g];
  unsigned short* WT = a.T[g];
  float sc = (g == 3 || g == 4) ? KSC2f : 1.0f;
  __shared__ float tile[32][33];
  int tx = threadIdx.x & 31, ty = threadIdx.x >> 5;
#pragma unroll
  for (int i = 0; i < 32; i += 8)
    tile[ty + i][tx] = W[(size_t)(k0 + ty + i) * N + n0 + tx];
  __syncthreads();
#pragma unroll
  for (int i = 0; i < 32; i += 8)
    WT[(size_t)(n0 + ty + i) * K + k0 + tx] = f2b(tile[tx][ty + i] * sc);
}

// ---------------- down-proj GEMM + fused Kr RoPE ----------------
// C1(8192 x 544) = xb(8192 x 1024) @ WT1(544 x 1024)^T.  grid (64,5).
// Cols 512..543 are kr_raw; for those (y==4, wc==0, j<2) the epilogue applies RoPE
// on the fp32 accumulators via __shfl_xor(1) lane-pairing and writes roped Krr
// directly -- deletes rope_qk's Kr pass. Pair (2i,2i+1) = (ln even, ln odd), same
// row (row independent of ln), wc/j selection wave-uniform -> no divergent shfl.
__global__ __launch_bounds__(256) void gemm_dq(const unsigned short* __restrict__ A,
                                               const unsigned short* __restrict__ Bt,
                                               unsigned short* __restrict__ C1,
                                               unsigned short* __restrict__ Krr) {
  __shared__ __align__(16) unsigned short As[128 * 32];
  __shared__ __align__(16) unsigned short Bs[128 * 32];
  const int t = threadIdx.x;
  const int w = t >> 6, lane = t & 63, ln = lane & 15, quad = lane >> 4;
  const int wr = w >> 1, wc = w & 1;
  const int bm0 = blockIdx.x * 128, bn0 = blockIdx.y * 128;
  const int srow = t >> 2, scol = (t & 3) * 8;
  f32x4 zero = {0.f, 0.f, 0.f, 0.f};
  f32x4 acc[4][4];
#pragma unroll
  for (int i = 0; i < 4; ++i)
#pragma unroll
    for (int j = 0; j < 4; ++j) acc[i][j] = zero;

  for (int k0 = 0; k0 < 1024; k0 += 32) {
#pragma unroll
    for (int r = 0; r < 2; ++r) {
      load_lds16(A + (long)(bm0 + r * 64 + srow) * 1024 + k0 + scol, (char*)As + r * 4096 + w * 1024);
      int brow = bn0 + r * 64 + srow;
      if (brow > 543) brow = 543;  // clamp (garbage cols guarded at write)
      load_lds16(Bt + (long)brow * 1024 + k0 + scol, (char*)Bs + r * 4096 + w * 1024);
    }
    __syncthreads();
    bf16x8 af[4], bf[4];
#pragma unroll
    for (int i = 0; i < 4; ++i)
      af[i] = *(const bf16x8*)(As + (wr * 64 + i * 16 + ln) * 32 + quad * 8);
#pragma unroll
    for (int j = 0; j < 4; ++j)
      bf[j] = *(const bf16x8*)(Bs + (wc * 64 + j * 16 + ln) * 32 + quad * 8);
#pragma unroll
    for (int i = 0; i < 4; ++i)
#pragma unroll
      for (int j = 0; j < 4; ++j) acc[i][j] = mfma16(af[i], bf[j], acc[i][j]);
    __syncthreads();
  }
  const bool kr = (blockIdx.y == 4) && (wc == 0);   // wave-uniform
#pragma unroll
  for (int i = 0; i < 4; ++i)
#pragma unroll
    for (int j = 0; j < 4; ++j)
#pragma unroll
      for (int r = 0; r < 4; ++r) {
        int row = bm0 + wr * 64 + i * 16 + quad * 4 + r;
        int col = bn0 + wc * 64 + j * 16 + ln;
        float v = acc[i][j][r];
        if (kr && j < 2) {
          float pv = __shfl_xor(v, 1);
          int kc = j * 16 + ln;                       // 0..31 within Kr
          float inv = exp2f(-(float)(kc >> 1) * RINVf);
          float ang = (float)(row & 2047) * inv;
          float c = cosf(ang), sn = sinf(ang);
          float out = (ln & 1) ? fmaf(pv, sn, v * c) : fmaf(v, c, -(pv * sn));
          Krr[(size_t)row * 32 + kc] = f2b(out);
        }
        if (col < 544)
          C1[(long)row * 544 + col] = f2b(v);
      }
}

// ---------------- merged mid GEMM: Q up-proj (+fused Qr RoPE) AND KV up-proj ----------------
// grid (64, 28), all K=256:
//  y in [0,12):  C2(8192x1536) = C1 @ WT2^T; for y>=8 (cols 1024..1535 = Qr region)
//                the epilogue applies RoPE on fp32 acc (shfl_xor pairing) -- deletes
//                rope_qk's Qr pass.
//  y in [12,20): C3 = c_kv @ W_UK^T, row-major bf16 write.
//  y in [20,28): V  = c_kv @ W_UV^T, transposed packed write to Vt[bh*64+d][s].
__global__ __launch_bounds__(256) void gemm_mid(const unsigned short* __restrict__ C1,
                                                const unsigned short* __restrict__ WT2,
                                                const unsigned short* __restrict__ WT3,
                                                unsigned short* __restrict__ C2,
                                                unsigned short* __restrict__ C3,
                                                unsigned short* __restrict__ Vt) {
  __shared__ __align__(16) unsigned short As[128 * 32];
  __shared__ __align__(16) unsigned short Bs[128 * 32];
  const int t = threadIdx.x;
  const int w = t >> 6, lane = t & 63, ln = lane & 15, quad = lane >> 4;
  const int wr = w >> 1, wc = w & 1;
  const int y = blockIdx.y;
  const unsigned short* A;
  const unsigned short* Bt;
  int bn0;
  if (y < 12)      { A = C1;       Bt = WT2;                       bn0 = y * 128; }
  else if (y < 20) { A = C1 + 256; Bt = WT3;                       bn0 = (y - 12) * 128; }
  else             { A = C1 + 256; Bt = WT3 + (size_t)1024 * 256;  bn0 = (y - 20) * 128; }
  const int bm0 = blockIdx.x * 128;
  const int srow = t >> 2, scol = (t & 3) * 8;
  f32x4 zero = {0.f, 0.f, 0.f, 0.f};
  f32x4 acc[4][4];
#pragma unroll
  for (int i = 0; i < 4; ++i)
#pragma unroll
    for (int j = 0; j < 4; ++j) acc[i][j] = zero;

  for (int k0 = 0; k0 < 256; k0 += 32) {
#pragma unroll
    for (int r = 0; r < 2; ++r) {
      load_lds16(A + (long)(bm0 + r * 64 + srow) * 544 + k0 + scol, (char*)As + r * 4096 + w * 1024);
      load_lds16(Bt + (long)(bn0 + r * 64 + srow) * 256 + k0 + scol, (char*)Bs + r * 4096 + w * 1024);
    }
    __syncthreads();
    bf16x8 af[4], bf[4];
#pragma unroll
    for (int i = 0; i < 4; ++i)
      af[i] = *(const bf16x8*)(As + (wr * 64 + i * 16 + ln) * 32 + quad * 8);
#pragma unroll
    for (int j = 0; j < 4; ++j)
      bf[j] = *(const bf16x8*)(Bs + (wc * 64 + j * 16 + ln) * 32 + quad * 8);
#pragma unroll
    for (int i = 0; i < 4; ++i)
#pragma unroll
      for (int j = 0; j < 4; ++j) acc[i][j] = mfma16(af[i], bf[j], acc[i][j]);
    __syncthreads();
  }

  if (y < 8) {                       // plain Qc region of C2
#pragma unroll
    for (int i = 0; i < 4; ++i)
#pragma unroll
      for (int j = 0; j < 4; ++j)
#pragma unroll
        for (int r = 0; r < 4; ++r) {
          int row = bm0 + wr * 64 + i * 16 + quad * 4 + r;
          int col = bn0 + wc * 64 + j * 16 + ln;
          C2[(long)row * 1536 + col] = f2b(acc[i][j][r]);
        }
  } else if (y < 12) {               // Qr region: fused RoPE (fp32 domain)
#pragma unroll
    for (int i = 0; i < 4; ++i)
#pragma unroll
      for (int j = 0; j < 4; ++j)
#pragma unroll
        for (int r = 0; r < 4; ++r) {
          int row = bm0 + wr * 64 + i * 16 + quad * 4 + r;
          int col = bn0 + wc * 64 + j * 16 + ln;
          float v = acc[i][j][r];
          float pv = __shfl_xor(v, 1);
          int hc = ((j & 1) << 4) | ln;               // (col-1024) & 31
          float inv = exp2f(-(float)(hc >> 1) * RINVf);
          float ang = (float)(row & 2047) * inv;
          float c = cosf(ang), sn = sinf(ang);
          float out = (ln & 1) ? fmaf(pv, sn, v * c) : fmaf(v, c, -(pv * sn));
          C2[(long)row * 1536 + col] = f2b(out);
        }
  } else if (y < 20) {               // Kc -> C3 row-major
#pragma unroll
    for (int i = 0; i < 4; ++i)
#pragma unroll
      for (int j = 0; j < 4; ++j)
#pragma unroll
        for (int r = 0; r < 4; ++r) {
          int row = bm0 + wr * 64 + i * 16 + quad * 4 + r;
          int col = bn0 + wc * 64 + j * 16 + ln;
          C3[(long)row * 1024 + col] = f2b(acc[i][j][r]);
        }
  } else {                           // V -> Vt transposed packed
#pragma unroll
    for (int i = 0; i < 4; ++i)
#pragma unroll
      for (int j = 0; j < 4; ++j) {
        int col = bn0 + wc * 64 + j * 16 + ln;          // 0..1023 = h*64+d
        int row0 = bm0 + wr * 64 + i * 16 + quad * 4;   // 4 consecutive seq rows, same b
        int b = row0 >> 11, sl = row0 & 2047;
        us4 pk = { f2b(acc[i][j][0]), f2b(acc[i][j][1]), f2b(acc[i][j][2]), f2b(acc[i][j][3]) };
        *(us4*)(Vt + ((size_t)(b * 16) * 64 + col) * 2048 + sl) = pk;
      }
  }
}

// ---------------- generic GEMM (used for the output projection only) ----------------
template <bool OUT_BF16>
__global__ __launch_bounds__(256) void gemm_bt(const unsigned short* __restrict__ A, int lda,
                                               const unsigned short* __restrict__ Bt, int ldb,
                                               void* __restrict__ Cv, int ldc, int N, int K) {
  __shared__ __align__(16) unsigned short As[128 * 32];
  __shared__ __align__(16) unsigned short Bs[128 * 32];
  const int t = threadIdx.x;
  const int w = t >> 6, lane = t & 63, ln = lane & 15, quad = lane >> 4;
  const int wr = w >> 1, wc = w & 1;
  const int bm0 = blockIdx.x * 128, bn0 = blockIdx.y * 128;
  const int srow = t >> 2, scol = (t & 3) * 8;
  f32x4 zero = {0.f, 0.f, 0.f, 0.f};
  f32x4 acc[4][4];
#pragma unroll
  for (int i = 0; i < 4; ++i)
#pragma unroll
    for (int j = 0; j < 4; ++j) acc[i][j] = zero;

  for (int k0 = 0; k0 < K; k0 += 32) {
#pragma unroll
    for (int r = 0; r < 2; ++r) {
      load_lds16(A + (long)(bm0 + r * 64 + srow) * lda + k0 + scol, (char*)As + r * 4096 + w * 1024);
      int brow = bn0 + r * 64 + srow;
      if (brow > N - 1) brow = N - 1;
      load_lds16(Bt + (long)brow * ldb + k0 + scol, (char*)Bs + r * 4096 + w * 1024);
    }
    __syncthreads();
    bf16x8 af[4], bf[4];
#pragma unroll
    for (int i = 0; i < 4; ++i)
      af[i] = *(const bf16x8*)(As + (wr * 64 + i * 16 + ln) * 32 + quad * 8);
#pragma unroll
    for (int j = 0; j < 4; ++j)
      bf[j] = *(const bf16x8*)(Bs + (wc * 64 + j * 16 + ln) * 32 + quad * 8);
#pragma unroll
    for (int i = 0; i < 4; ++i)
#pragma unroll
      for (int j = 0; j < 4; ++j) acc[i][j] = mfma16(af[i], bf[j], acc[i][j]);
    __syncthreads();
  }
#pragma unroll
  for (int i = 0; i < 4; ++i)
#pragma unroll
    for (int j = 0; j < 4; ++j)
#pragma unroll
      for (int r = 0; r < 4; ++r) {
        int row = bm0 + wr * 64 + i * 16 + quad * 4 + r;
        int col = bn0 + wc * 64 + j * 16 + ln;
        if (col < N) {
          if (OUT_BF16)
            ((unsigned short*)Cv)[(long)row * ldc + col] = f2b(acc[i][j][r]);
          else
            ((float*)Cv)[(long)row * ldc + col] = acc[i][j][r];
        }
      }
}

// ---------------- Flash attention (R4/R6/R9 version verbatim -- 95.5-97.9us) ----------
//  * qi = 15 - blockIdx.y (longest first), grid (64,16)
//  * kr loads issued post-barrier, before stage(kt+1)
//  * zero-conflict LDS swizzle ^(r&7)^(r>>3)
//  * KSC2 prescale (in W_UQ/W_QR), clip in scaled domain, no KOFF2
//  * row sums via ones-column MFMA; epilogue 1/osum[p], no exchange
//  * __launch_bounds__(256,3): (256,4) caps VGPR at 64 -> catastrophic spill (R3);
//    hand-hoisting/pinning regs re-spills (R7). Leave allocation to the compiler.
__global__ __launch_bounds__(256, 3) void flash_attn(const unsigned short* __restrict__ C2,
                                                     const unsigned short* __restrict__ C3,
                                                     const unsigned short* __restrict__ Krr,
                                                     const unsigned short* __restrict__ Vt,
                                                     unsigned short* __restrict__ Oa) {
  __shared__ __align__(16) unsigned short Ks[2][4096];  // 64 keys(pi-staged) x 64 d, swizzled
  __shared__ __align__(16) unsigned short Vs[2][4096];  // 64 d x 64 keys(natural), swizzled

  const int tid = threadIdx.x;
  const int w = tid >> 6, lane = tid & 63;
  const int l31 = lane & 31, h = lane >> 5;
  const int bh = blockIdx.x, b = bh >> 4, head = bh & 15;
  const int bS = b * 2048;
  const int qi = 15 - (int)blockIdx.y;
  const int qb = qi * 128 + w * 32;
  const int nkt = 2 * qi + 2;
  const int q = qb + l31;               // this lane's q row
  const int pr = (l31 & ~12) | ((l31 & 4) << 1) | ((l31 & 8) >> 1);  // pi(l31)

  // Q B-operand fragments (pre-scaled by KSC2): per lane row q, 8 d's at h*8.
  const unsigned short* qp = C2 + (size_t)(bS + q) * 1536;
  bf16x8 qf[6];
#pragma unroll
  for (int c = 0; c < 4; ++c)
    qf[c] = *(const bf16x8*)(qp + head * 64 + c * 16 + h * 8);
#pragma unroll
  for (int c = 4; c < 6; ++c)
    qf[c] = *(const bf16x8*)(qp + 1024 + head * 32 + (c - 4) * 16 + h * 8);

  // ones B-operand for row-sum MFMA
  union { unsigned short u[8]; bf16x8 v; } onesu;
#pragma unroll
  for (int i = 0; i < 8; ++i) onesu.u[i] = 0x3F80;  // bf16 1.0
  const bf16x8 ones = onesu.v;

  f32x16 o0 = {}, o1 = {}, osum = {};

  auto stage = [&](int buf, int key0) {
#pragma unroll
    for (int t = w; t < 8; t += 4) {   // K: dest row r <- source key key0+pi(r)
      int ci = t * 64 + lane;
      int r = ci >> 3, sl = ci & 7;
      int srcc = sl ^ (r & 7) ^ (r >> 3);
      int srck = (r & ~12) | ((r & 4) << 1) | ((r & 8) >> 1);
      load_lds16(C3 + (size_t)(bS + key0 + srck) * 1024 + head * 64 + srcc * 8,
                 &Ks[buf][t * 512]);
    }
#pragma unroll
    for (int t = w; t < 8; t += 4) {   // V^T: natural key order
      int ci = t * 64 + lane;
      int r = ci >> 3, sl = ci & 7;
      int srcc = sl ^ (r & 7) ^ (r >> 3);
      load_lds16(Vt + (size_t)((size_t)bh * 64 + r) * 2048 + key0 + srcc * 8,
                 &Vs[buf][t * 512]);
    }
  };

  stage(0, 0);
  for (int kt = 0; kt < nkt; ++kt) {
    __syncthreads();                    // drains vmcnt(0): stage(kt) visible
    const int c0 = kt * 64;
    const bool live = (c0 <= qb + 31);
    bf16x8 kr[4];                       // Kr A-frags from global (pi rows), BEFORE next stage
    if (live) {
#pragma unroll
      for (int m = 0; m < 2; ++m)
#pragma unroll
        for (int c = 0; c < 2; ++c)
          kr[m * 2 + c] = *(const bf16x8*)(Krr + (size_t)(bS + c0 + m * 32 + pr) * 32 +
                                           c * 16 + h * 8);
    }
    if (kt + 1 < nkt) stage((kt + 1) & 1, c0 + 64);
    if (!live) continue;

    const unsigned short* Kp = Ks[kt & 1];
    const unsigned short* Vp = Vs[kt & 1];

#pragma unroll
    for (int m = 0; m < 2; ++m) {
      if (c0 + m * 32 > qb + 31) continue;   // m-tile fully masked for this wave
      const int r = m * 32 + l31;            // staged K row this lane reads
      f32x16 s = {};
#pragma unroll
      for (int c = 0; c < 4; ++c) {
        int slot = (2 * c + h) ^ (r & 7) ^ (r >> 3);
        bf16x8 kf = *(const bf16x8*)(Kp + r * 64 + slot * 8);
        s = mfma32(kf, qf[c], s);
      }
      s = mfma32(kr[m * 2 + 0], qf[4], s);
      s = mfma32(kr[m * 2 + 1], qf[5], s);

      // exp in-register; actual key of reg p = c0+m*32+(p&3)+4*((p>>2)&1)+8h+16*(p>>3)
      const bool nm = (c0 + m * 32 + 31) > qb;   // touches diagonal for this wave
      float ev[16];
#pragma unroll
      for (int p = 0; p < 16; ++p) {
        float z = __builtin_amdgcn_fmed3f(s[p], -CLIPf, CLIPf);  // clip (scaled domain)
        if (nm) {
          int key = c0 + m * 32 + (p & 3) + 4 * ((p >> 2) & 1) + 8 * h + 16 * (p >> 3);
          if (key > q) z = -1e30f;
        }
        ev[p] = exp2f(z);
      }
      bf16x8 pf[2];
#pragma unroll
      for (int t = 0; t < 2; ++t) {
        union { unsigned int u[4]; bf16x8 v; } pk;
#pragma unroll
        for (int j = 0; j < 4; ++j)
          pk.u[j] = f2b2(ev[t * 8 + 2 * j], ev[t * 8 + 2 * j + 1]);
        pf[t] = pk.v;
      }
      // PV: A = pf (keys natural order by pi-identity), B = V fragments from Vs.
      // Row sums ride the MFMA pipe: osum += P @ ones.
#pragma unroll
      for (int t = 0; t < 2; ++t) {
        int tk = m * 2 + t;
        osum = mfma32(pf[t], ones, osum);
#pragma unroll
        for (int n = 0; n < 2; ++n) {
          int rr = n * 32 + l31;
          int slot = (2 * tk + h) ^ (rr & 7) ^ (rr >> 3);
          bf16x8 vf = *(const bf16x8*)(Vp + rr * 64 + slot * 8);
          if (n == 0) o0 = mfma32(pf[t], vf, o0);
          else        o1 = mfma32(pf[t], vf, o1);
        }
      }
    }
  }

  // ---- epilogue: osum[p] is the full row sum for row qrow; no exchange needed ----
#pragma unroll
  for (int p = 0; p < 16; ++p) {
    int qrow = (p & 3) + 8 * (p >> 2) + 4 * h;  // o C-layout row
    float rl = 1.0f / osum[p];
    size_t base = (size_t)(bS + qb + qrow) * 1024 + head * 64;
    Oa[base + l31]      = f2b(o0[p] * rl);
    Oa[base + 32 + l31] = f2b(o1[p] * rl);
  }
}

// ---------------- launcher ----------------
extern "C" void kernel_launch(void* const* d_in, const int* in_sizes, int n_in,
                              void* d_out, int out_size, void* d_ws, size_t ws_size,
                              hipStream_t stream) {
  (void)in_sizes; (void)n_in; (void)out_size; (void)ws_size;
  const float* x     = (const float*)d_in[0];
  const float* W_DQ  = (const float*)d_in[1];
  const float* W_UQ  = (const float*)d_in[2];
  const float* W_QR  = (const float*)d_in[3];
  const float* W_DKV = (const float*)d_in[4];
  const float* W_UK  = (const float*)d_in[5];
  const float* W_UV  = (const float*)d_in[6];
  const float* W_KR  = (const float*)d_in[7];
  const float* W_O   = (const float*)d_in[8];

  char* p = (char*)d_ws;
  unsigned short* xb  = (unsigned short*)p; p += (size_t)8192 * 1024 * 2;
  unsigned short* WT1 = (unsigned short*)p; p += (size_t)544 * 1024 * 2;   // [W_DQ^T; W_DKV^T; W_KR^T]
  unsigned short* WT2 = (unsigned short*)p; p += (size_t)1536 * 256 * 2;   // [W_UQ^T; W_QR^T] (KSC2-scaled)
  unsigned short* WT3 = (unsigned short*)p; p += (size_t)2048 * 256 * 2;   // [W_UK^T; W_UV^T]
  unsigned short* WT4 = (unsigned short*)p; p += (size_t)1024 * 1024 * 2;  // W_O^T
  unsigned short* C1  = (unsigned short*)p; p += (size_t)8192 * 544 * 2;   // [c_q | c_kv | kr_raw]
  unsigned short* C2  = (unsigned short*)p; p += (size_t)8192 * 1536 * 2;  // [Qc | Qr (roped at write)]
  unsigned short* C3  = (unsigned short*)p; p += (size_t)8192 * 1024 * 2;  // Kc only
  unsigned short* Krr = (unsigned short*)p; p += (size_t)8192 * 32 * 2;    // roped Kr
  unsigned short* Vt  = (unsigned short*)p; p += (size_t)64 * 64 * 2048 * 2;
  unsigned short* Oa  = (unsigned short*)p; p += (size_t)8192 * 1024 * 2;  // attn out (B,S,1024)

  TWArgs tw;
  tw.W[0] = W_DQ;  tw.T[0] = WT1;
  tw.W[1] = W_DKV; tw.T[1] = WT1 + 256 * 1024;
  tw.W[2] = W_KR;  tw.T[2] = WT1 + 512 * 1024;
  tw.W[3] = W_UQ;  tw.T[3] = WT2;
  tw.W[4] = W_QR;  tw.T[4] = WT2 + 1024 * 256;
  tw.W[5] = W_UK;  tw.T[5] = WT3;
  tw.W[6] = W_UV;  tw.T[6] = WT3 + 1024 * 256;
  tw.W[7] = W_O;   tw.T[7] = WT4;
  prep<<<8192 + 2464, 256, 0, stream>>>(x, xb, tw);

  gemm_dq<<<dim3(64, 5),   256, 0, stream>>>(xb, WT1, C1, Krr);
  gemm_mid<<<dim3(64, 28), 256, 0, stream>>>(C1, WT2, WT3, C2, C3, Vt);
  flash_attn<<<dim3(64, 16), 256, 0, stream>>>(C2, C3, Krr, Vt, Oa);
  gemm_bt<false><<<dim3(64, 8), 256, 0, stream>>>(Oa, 1024, WT4, 1024, d_out, 1024, 1024, 1024);
}

// Round 11
// 270.054 us; speedup vs baseline: 1.9173x; 1.9173x over previous
//
#include <hip/hip_runtime.h>
#include <hip/hip_bf16.h>

// MLA forward, MI355X/gfx950.
// B=4, S=2048, D_MODEL=1024, H=16, D_H=64, D_HR=32, D_LATENT=256, d_qk=96.
//
// R11 = R9 structure (276.8us, reproduced) + ONE retained change: gemm2+gemm_kv
// merged into trig-free gemm_mid. R10's rope-fused epilogues are REVERTED: the
// epilogue trig (row/col-dependent cos/sin) got LICM-hoisted above the K-loop,
// poisoning register allocation kernel-wide -> in-loop acc spill, 350-900 MB of
// scratch writes, 3x slowdown. rope_qk restored as its own dispatch.

typedef __attribute__((ext_vector_type(8))) __bf16 bf16x8;
typedef __attribute__((ext_vector_type(4))) float f32x4;
typedef __attribute__((ext_vector_type(16))) float f32x16;
typedef __attribute__((ext_vector_type(4))) unsigned short us4;

#define DEV static __device__ __forceinline__

DEV unsigned short f2b(float f) {
  union { __hip_bfloat16 h; unsigned short u; } v;
  v.h = __float2bfloat16(f);
  return v.u;
}
DEV float b2f(unsigned short u) {
  union { unsigned short u; __hip_bfloat16 h; } v;
  v.u = u;
  return __bfloat162float(v.h);
}
DEV unsigned int f2b2(float lo, float hi) {   // packed 2xf32 -> 2xbf16
  union { __hip_bfloat162 h2; unsigned int u; } v;
  float2 t; t.x = lo; t.y = hi;
  v.h2 = __float22bfloat162_rn(t);
  return v.u;
}
DEV f32x4 mfma16(bf16x8 a, bf16x8 b, f32x4 c) {
  return __builtin_amdgcn_mfma_f32_16x16x32_bf16(a, b, c, 0, 0, 0);
}
DEV f32x16 mfma32(bf16x8 a, bf16x8 b, f32x16 c) {
  return __builtin_amdgcn_mfma_f32_32x32x16_bf16(a, b, c, 0, 0, 0);
}
DEV void load_lds16(const void* g, void* lds) {
  __builtin_amdgcn_global_load_lds((__attribute__((address_space(1))) void*)g,
                                   (__attribute__((address_space(3))) void*)lds,
                                   16, 0, 0);
}

// Q-side prescale folded into W_UQ^T / W_QR^T: (1/sqrt(96)) * log2(e).
#define KSC2f 0.14724444690f
// Clip bound in the scaled domain: 80 * KSC2.
#define CLIPf 11.7795557220f

// ---------------- prep: convert x (fp32->bf16) + 8 weight transposes, ONE dispatch ----------
struct TWArgs { const float* W[8]; unsigned short* T[8]; };
__global__ __launch_bounds__(256) void prep(const float* __restrict__ x,
                                            unsigned short* __restrict__ xb, TWArgs a) {
  if (blockIdx.x < 8192) {
    long i = (long)(blockIdx.x * 256 + threadIdx.x) * 4;
    float4 v = *(const float4*)(x + i);
    us4 o = { f2b(v.x), f2b(v.y), f2b(v.z), f2b(v.w) };
    *(us4*)(xb + i) = o;
    return;
  }
  int bid = blockIdx.x - 8192;
  int g;
  if      (bid < 256)  g = 0;
  else if (bid < 512)  g = 1;
  else if (bid < 544)  g = 2;
  else if (bid < 800)  g = 3;
  else if (bid < 928)  g = 4;
  else if (bid < 1184) g = 5;
  else if (bid < 1440) g = 6;
  else                 g = 7;
  const int starts[8] = {0, 256, 512, 544, 800, 928, 1184, 1440};
  int local = bid - starts[g];
  int K = (g >= 3 && g <= 6) ? 256 : 1024;
  int N = (g < 2) ? 256 : (g == 2 ? 32 : (g == 4 ? 512 : 1024));
  int tilesX = N >> 5;
  int n0 = (local % tilesX) * 32, k0 = (local / tilesX) * 32;
  const float* W = a.W[g];
  unsigned short* WT = a.T[g];
  float sc = (g == 3 || g == 4) ? KSC2f : 1.0f;
  __shared__ float tile[32][33];
  int tx = threadIdx.x & 31, ty = threadIdx.x >> 5;
#pragma unroll
  for (int i = 0; i < 32; i += 8)
    tile[ty + i][tx] = W[(size_t)(k0 + ty + i) * N + n0 + tx];
  __syncthreads();
#pragma unroll
  for (int i = 0; i < 32; i += 8)
    WT[(size_t)(n0 + ty + i) * K + k0 + tx] = f2b(tile[tx][ty + i] * sc);
}

// ---------------- fused RoPE: Qr in-place in C2, Kr C1->Krr (R9 version) ----------------
__global__ __launch_bounds__(256) void rope_qk(unsigned short* __restrict__ C2,
                                               const unsigned short* __restrict__ C1,
                                               unsigned short* __restrict__ Krr) {
  if (blockIdx.x < 8192) {
    int idx = blockIdx.x * 256 + threadIdx.x;   // 2^21 threads exact
    int i = idx & 15, h = (idx >> 4) & 15, s = (idx >> 8) & 2047, b = idx >> 19;
    long base = (long)(b * 2048 + s) * 1536 + 1024 + h * 32 + 2 * i;
    float x1 = b2f(C2[base]), x2 = b2f(C2[base + 1]);
    float inv = exp2f(-(float)i * 0.8304820237686285f);  // 10000^(-i/16)
    float ang = (float)s * inv;
    float c = cosf(ang), sn = sinf(ang);
    C2[base]     = f2b(x1 * c - x2 * sn);
    C2[base + 1] = f2b(x1 * sn + x2 * c);
  } else {
    int idx = (blockIdx.x - 8192) * 256 + threadIdx.x;   // 2^17 threads exact
    int i = idx & 15, s = (idx >> 4) & 2047, b = idx >> 15;
    long src = (long)(b * 2048 + s) * 544 + 512 + 2 * i;
    float x1 = b2f(C1[src]), x2 = b2f(C1[src + 1]);
    float inv = exp2f(-(float)i * 0.8304820237686285f);
    float ang = (float)s * inv;
    float c = cosf(ang), sn = sinf(ang);
    long dst = (long)(b * 2048 + s) * 32 + 2 * i;
    Krr[dst]     = f2b(x1 * c - x2 * sn);
    Krr[dst + 1] = f2b(x1 * sn + x2 * c);
  }
}

// ---------------- GEMM: C(M x N) = A(M x K, lda) @ Bt(N x K, ldb)^T ----------------
template <bool OUT_BF16>
__global__ __launch_bounds__(256) void gemm_bt(const unsigned short* __restrict__ A, int lda,
                                               const unsigned short* __restrict__ Bt, int ldb,
                                               void* __restrict__ Cv, int ldc, int N, int K) {
  __shared__ __align__(16) unsigned short As[128 * 32];
  __shared__ __align__(16) unsigned short Bs[128 * 32];
  const int t = threadIdx.x;
  const int w = t >> 6, lane = t & 63, ln = lane & 15, quad = lane >> 4;
  const int wr = w >> 1, wc = w & 1;
  const int bm0 = blockIdx.x * 128, bn0 = blockIdx.y * 128;
  const int srow = t >> 2, scol = (t & 3) * 8;
  f32x4 zero = {0.f, 0.f, 0.f, 0.f};
  f32x4 acc[4][4];
#pragma unroll
  for (int i = 0; i < 4; ++i)
#pragma unroll
    for (int j = 0; j < 4; ++j) acc[i][j] = zero;

  for (int k0 = 0; k0 < K; k0 += 32) {
#pragma unroll
    for (int r = 0; r < 2; ++r) {
      load_lds16(A + (long)(bm0 + r * 64 + srow) * lda + k0 + scol, (char*)As + r * 4096 + w * 1024);
      int brow = bn0 + r * 64 + srow;
      if (brow > N - 1) brow = N - 1;  // clamp (garbage cols guarded at write)
      load_lds16(Bt + (long)brow * ldb + k0 + scol, (char*)Bs + r * 4096 + w * 1024);
    }
    __syncthreads();
    bf16x8 af[4], bf[4];
#pragma unroll
    for (int i = 0; i < 4; ++i)
      af[i] = *(const bf16x8*)(As + (wr * 64 + i * 16 + ln) * 32 + quad * 8);
#pragma unroll
    for (int j = 0; j < 4; ++j)
      bf[j] = *(const bf16x8*)(Bs + (wc * 64 + j * 16 + ln) * 32 + quad * 8);
#pragma unroll
    for (int i = 0; i < 4; ++i)
#pragma unroll
      for (int j = 0; j < 4; ++j) acc[i][j] = mfma16(af[i], bf[j], acc[i][j]);
    __syncthreads();
  }
#pragma unroll
  for (int i = 0; i < 4; ++i)
#pragma unroll
    for (int j = 0; j < 4; ++j)
#pragma unroll
      for (int r = 0; r < 4; ++r) {
        int row = bm0 + wr * 64 + i * 16 + quad * 4 + r;
        int col = bn0 + wc * 64 + j * 16 + ln;
        if (col < N) {
          if (OUT_BF16)
            ((unsigned short*)Cv)[(long)row * ldc + col] = f2b(acc[i][j][r]);
          else
            ((float*)Cv)[(long)row * ldc + col] = acc[i][j][r];
        }
      }
}

// ---------------- merged mid GEMM (trig-free): Q up-proj AND KV up-proj ----------------
// grid (64, 28), all K=256, no clamps (exact bounds per branch), PLAIN epilogues only:
//  y in [0,12):  C2(8192x1536) = c_q @ WT2^T, row-major bf16 (RoPE applied later by rope_qk)
//  y in [12,20): C3 = c_kv @ W_UK^T, row-major bf16
//  y in [20,28): V  = c_kv @ W_UV^T, transposed packed write to Vt[bh*64+d][s]
// R10 lesson: NO trig in epilogues -- it LICM-hoists above the K-loop and poisons
// regalloc for every block of the kernel (static allocation).
__global__ __launch_bounds__(256) void gemm_mid(const unsigned short* __restrict__ C1,
                                                const unsigned short* __restrict__ WT2,
                                                const unsigned short* __restrict__ WT3,
                                                unsigned short* __restrict__ C2,
                                                unsigned short* __restrict__ C3,
                                                unsigned short* __restrict__ Vt) {
  __shared__ __align__(16) unsigned short As[128 * 32];
  __shared__ __align__(16) unsigned short Bs[128 * 32];
  const int t = threadIdx.x;
  const int w = t >> 6, lane = t & 63, ln = lane & 15, quad = lane >> 4;
  const int wr = w >> 1, wc = w & 1;
  const int y = blockIdx.y;
  const unsigned short* A;
  const unsigned short* Bt;
  int bn0;
  if (y < 12)      { A = C1;       Bt = WT2;                       bn0 = y * 128; }
  else if (y < 20) { A = C1 + 256; Bt = WT3;                       bn0 = (y - 12) * 128; }
  else             { A = C1 + 256; Bt = WT3 + (size_t)1024 * 256;  bn0 = (y - 20) * 128; }
  const int bm0 = blockIdx.x * 128;
  const int srow = t >> 2, scol = (t & 3) * 8;
  f32x4 zero = {0.f, 0.f, 0.f, 0.f};
  f32x4 acc[4][4];
#pragma unroll
  for (int i = 0; i < 4; ++i)
#pragma unroll
    for (int j = 0; j < 4; ++j) acc[i][j] = zero;

  for (int k0 = 0; k0 < 256; k0 += 32) {
#pragma unroll
    for (int r = 0; r < 2; ++r) {
      load_lds16(A + (long)(bm0 + r * 64 + srow) * 544 + k0 + scol, (char*)As + r * 4096 + w * 1024);
      load_lds16(Bt + (long)(bn0 + r * 64 + srow) * 256 + k0 + scol, (char*)Bs + r * 4096 + w * 1024);
    }
    __syncthreads();
    bf16x8 af[4], bf[4];
#pragma unroll
    for (int i = 0; i < 4; ++i)
      af[i] = *(const bf16x8*)(As + (wr * 64 + i * 16 + ln) * 32 + quad * 8);
#pragma unroll
    for (int j = 0; j < 4; ++j)
      bf[j] = *(const bf16x8*)(Bs + (wc * 64 + j * 16 + ln) * 32 + quad * 8);
#pragma unroll
    for (int i = 0; i < 4; ++i)
#pragma unroll
      for (int j = 0; j < 4; ++j) acc[i][j] = mfma16(af[i], bf[j], acc[i][j]);
    __syncthreads();
  }

  if (y < 12) {                      // C2 row-major (Qc + raw Qr; rope_qk ropes Qr later)
#pragma unroll
    for (int i = 0; i < 4; ++i)
#pragma unroll
      for (int j = 0; j < 4; ++j)
#pragma unroll
        for (int r = 0; r < 4; ++r) {
          int row = bm0 + wr * 64 + i * 16 + quad * 4 + r;
          int col = bn0 + wc * 64 + j * 16 + ln;
          C2[(long)row * 1536 + col] = f2b(acc[i][j][r]);
        }
  } else if (y < 20) {               // Kc -> C3 row-major
#pragma unroll
    for (int i = 0; i < 4; ++i)
#pragma unroll
      for (int j = 0; j < 4; ++j)
#pragma unroll
        for (int r = 0; r < 4; ++r) {
          int row = bm0 + wr * 64 + i * 16 + quad * 4 + r;
          int col = bn0 + wc * 64 + j * 16 + ln;
          C3[(long)row * 1024 + col] = f2b(acc[i][j][r]);
        }
  } else {                           // V -> Vt transposed packed
#pragma unroll
    for (int i = 0; i < 4; ++i)
#pragma unroll
      for (int j = 0; j < 4; ++j) {
        int col = bn0 + wc * 64 + j * 16 + ln;          // 0..1023 = h*64+d
        int row0 = bm0 + wr * 64 + i * 16 + quad * 4;   // 4 consecutive seq rows, same b
        int b = row0 >> 11, sl = row0 & 2047;
        us4 pk = { f2b(acc[i][j][0]), f2b(acc[i][j][1]), f2b(acc[i][j][2]), f2b(acc[i][j][3]) };
        *(us4*)(Vt + ((size_t)(b * 16) * 64 + col) * 2048 + sl) = pk;
      }
  }
}

// ---------------- Flash attention (R4/R6/R9 version verbatim -- 95.5-97.9us) ----------
//  * qi = 15 - blockIdx.y (longest first), grid (64,16)
//  * kr loads issued post-barrier, before stage(kt+1)
//  * zero-conflict LDS swizzle ^(r&7)^(r>>3)
//  * KSC2 prescale (in W_UQ/W_QR), clip in scaled domain, no KOFF2
//  * row sums via ones-column MFMA; epilogue 1/osum[p], no exchange
//  * __launch_bounds__(256,3): (256,4) caps VGPR at 64 -> catastrophic spill (R3);
//    hand-hoisting/pinning regs re-spills (R7). Leave allocation to the compiler.
__global__ __launch_bounds__(256, 3) void flash_attn(const unsigned short* __restrict__ C2,
                                                     const unsigned short* __restrict__ C3,
                                                     const unsigned short* __restrict__ Krr,
                                                     const unsigned short* __restrict__ Vt,
                                                     unsigned short* __restrict__ Oa) {
  __shared__ __align__(16) unsigned short Ks[2][4096];  // 64 keys(pi-staged) x 64 d, swizzled
  __shared__ __align__(16) unsigned short Vs[2][4096];  // 64 d x 64 keys(natural), swizzled

  const int tid = threadIdx.x;
  const int w = tid >> 6, lane = tid & 63;
  const int l31 = lane & 31, h = lane >> 5;
  const int bh = blockIdx.x, b = bh >> 4, head = bh & 15;
  const int bS = b * 2048;
  const int qi = 15 - (int)blockIdx.y;
  const int qb = qi * 128 + w * 32;
  const int nkt = 2 * qi + 2;
  const int q = qb + l31;               // this lane's q row
  const int pr = (l31 & ~12) | ((l31 & 4) << 1) | ((l31 & 8) >> 1);  // pi(l31)

  // Q B-operand fragments (pre-scaled by KSC2): per lane row q, 8 d's at h*8.
  const unsigned short* qp = C2 + (size_t)(bS + q) * 1536;
  bf16x8 qf[6];
#pragma unroll
  for (int c = 0; c < 4; ++c)
    qf[c] = *(const bf16x8*)(qp + head * 64 + c * 16 + h * 8);
#pragma unroll
  for (int c = 4; c < 6; ++c)
    qf[c] = *(const bf16x8*)(qp + 1024 + head * 32 + (c - 4) * 16 + h * 8);

  // ones B-operand for row-sum MFMA
  union { unsigned short u[8]; bf16x8 v; } onesu;
#pragma unroll
  for (int i = 0; i < 8; ++i) onesu.u[i] = 0x3F80;  // bf16 1.0
  const bf16x8 ones = onesu.v;

  f32x16 o0 = {}, o1 = {}, osum = {};

  auto stage = [&](int buf, int key0) {
#pragma unroll
    for (int t = w; t < 8; t += 4) {   // K: dest row r <- source key key0+pi(r)
      int ci = t * 64 + lane;
      int r = ci >> 3, sl = ci & 7;
      int srcc = sl ^ (r & 7) ^ (r >> 3);
      int srck = (r & ~12) | ((r & 4) << 1) | ((r & 8) >> 1);
      load_lds16(C3 + (size_t)(bS + key0 + srck) * 1024 + head * 64 + srcc * 8,
                 &Ks[buf][t * 512]);
    }
#pragma unroll
    for (int t = w; t < 8; t += 4) {   // V^T: natural key order
      int ci = t * 64 + lane;
      int r = ci >> 3, sl = ci & 7;
      int srcc = sl ^ (r & 7) ^ (r >> 3);
      load_lds16(Vt + (size_t)((size_t)bh * 64 + r) * 2048 + key0 + srcc * 8,
                 &Vs[buf][t * 512]);
    }
  };

  stage(0, 0);
  for (int kt = 0; kt < nkt; ++kt) {
    __syncthreads();                    // drains vmcnt(0): stage(kt) visible
    const int c0 = kt * 64;
    const bool live = (c0 <= qb + 31);
    bf16x8 kr[4];                       // Kr A-frags from global (pi rows), BEFORE next stage
    if (live) {
#pragma unroll
      for (int m = 0; m < 2; ++m)
#pragma unroll
        for (int c = 0; c < 2; ++c)
          kr[m * 2 + c] = *(const bf16x8*)(Krr + (size_t)(bS + c0 + m * 32 + pr) * 32 +
                                           c * 16 + h * 8);
    }
    if (kt + 1 < nkt) stage((kt + 1) & 1, c0 + 64);
    if (!live) continue;

    const unsigned short* Kp = Ks[kt & 1];
    const unsigned short* Vp = Vs[kt & 1];

#pragma unroll
    for (int m = 0; m < 2; ++m) {
      if (c0 + m * 32 > qb + 31) continue;   // m-tile fully masked for this wave
      const int r = m * 32 + l31;            // staged K row this lane reads
      f32x16 s = {};
#pragma unroll
      for (int c = 0; c < 4; ++c) {
        int slot = (2 * c + h) ^ (r & 7) ^ (r >> 3);
        bf16x8 kf = *(const bf16x8*)(Kp + r * 64 + slot * 8);
        s = mfma32(kf, qf[c], s);
      }
      s = mfma32(kr[m * 2 + 0], qf[4], s);
      s = mfma32(kr[m * 2 + 1], qf[5], s);

      // exp in-register; actual key of reg p = c0+m*32+(p&3)+4*((p>>2)&1)+8h+16*(p>>3)
      const bool nm = (c0 + m * 32 + 31) > qb;   // touches diagonal for this wave
      float ev[16];
#pragma unroll
      for (int p = 0; p < 16; ++p) {
        float z = __builtin_amdgcn_fmed3f(s[p], -CLIPf, CLIPf);  // clip (scaled domain)
        if (nm) {
          int key = c0 + m * 32 + (p & 3) + 4 * ((p >> 2) & 1) + 8 * h + 16 * (p >> 3);
          if (key > q) z = -1e30f;
        }
        ev[p] = exp2f(z);
      }
      bf16x8 pf[2];
#pragma unroll
      for (int t = 0; t < 2; ++t) {
        union { unsigned int u[4]; bf16x8 v; } pk;
#pragma unroll
        for (int j = 0; j < 4; ++j)
          pk.u[j] = f2b2(ev[t * 8 + 2 * j], ev[t * 8 + 2 * j + 1]);
        pf[t] = pk.v;
      }
      // PV: A = pf (keys natural order by pi-identity), B = V fragments from Vs.
      // Row sums ride the MFMA pipe: osum += P @ ones.
#pragma unroll
      for (int t = 0; t < 2; ++t) {
        int tk = m * 2 + t;
        osum = mfma32(pf[t], ones, osum);
#pragma unroll
        for (int n = 0; n < 2; ++n) {
          int rr = n * 32 + l31;
          int slot = (2 * tk + h) ^ (rr & 7) ^ (rr >> 3);
          bf16x8 vf = *(const bf16x8*)(Vp + rr * 64 + slot * 8);
          if (n == 0) o0 = mfma32(pf[t], vf, o0);
          else        o1 = mfma32(pf[t], vf, o1);
        }
      }
    }
  }

  // ---- epilogue: osum[p] is the full row sum for row qrow; no exchange needed ----
#pragma unroll
  for (int p = 0; p < 16; ++p) {
    int qrow = (p & 3) + 8 * (p >> 2) + 4 * h;  // o C-layout row
    float rl = 1.0f / osum[p];
    size_t base = (size_t)(bS + qb + qrow) * 1024 + head * 64;
    Oa[base + l31]      = f2b(o0[p] * rl);
    Oa[base + 32 + l31] = f2b(o1[p] * rl);
  }
}

// ---------------- launcher ----------------
extern "C" void kernel_launch(void* const* d_in, const int* in_sizes, int n_in,
                              void* d_out, int out_size, void* d_ws, size_t ws_size,
                              hipStream_t stream) {
  (void)in_sizes; (void)n_in; (void)out_size; (void)ws_size;
  const float* x     = (const float*)d_in[0];
  const float* W_DQ  = (const float*)d_in[1];
  const float* W_UQ  = (const float*)d_in[2];
  const float* W_QR  = (const float*)d_in[3];
  const float* W_DKV = (const float*)d_in[4];
  const float* W_UK  = (const float*)d_in[5];
  const float* W_UV  = (const float*)d_in[6];
  const float* W_KR  = (const float*)d_in[7];
  const float* W_O   = (const float*)d_in[8];

  char* p = (char*)d_ws;
  unsigned short* xb  = (unsigned short*)p; p += (size_t)8192 * 1024 * 2;
  unsigned short* WT1 = (unsigned short*)p; p += (size_t)544 * 1024 * 2;   // [W_DQ^T; W_DKV^T; W_KR^T]
  unsigned short* WT2 = (unsigned short*)p; p += (size_t)1536 * 256 * 2;   // [W_UQ^T; W_QR^T] (KSC2-scaled)
  unsigned short* WT3 = (unsigned short*)p; p += (size_t)2048 * 256 * 2;   // [W_UK^T; W_UV^T]
  unsigned short* WT4 = (unsigned short*)p; p += (size_t)1024 * 1024 * 2;  // W_O^T
  unsigned short* C1  = (unsigned short*)p; p += (size_t)8192 * 544 * 2;   // [c_q | c_kv | kr_raw]
  unsigned short* C2  = (unsigned short*)p; p += (size_t)8192 * 1536 * 2;  // [Qc | Qr(roped in-place)]
  unsigned short* C3  = (unsigned short*)p; p += (size_t)8192 * 1024 * 2;  // Kc only
  unsigned short* Krr = (unsigned short*)p; p += (size_t)8192 * 32 * 2;    // roped Kr
  unsigned short* Vt  = (unsigned short*)p; p += (size_t)64 * 64 * 2048 * 2;
  unsigned short* Oa  = (unsigned short*)p; p += (size_t)8192 * 1024 * 2;  // attn out (B,S,1024)

  TWArgs tw;
  tw.W[0] = W_DQ;  tw.T[0] = WT1;
  tw.W[1] = W_DKV; tw.T[1] = WT1 + 256 * 1024;
  tw.W[2] = W_KR;  tw.T[2] = WT1 + 512 * 1024;
  tw.W[3] = W_UQ;  tw.T[3] = WT2;
  tw.W[4] = W_QR;  tw.T[4] = WT2 + 1024 * 256;
  tw.W[5] = W_UK;  tw.T[5] = WT3;
  tw.W[6] = W_UV;  tw.T[6] = WT3 + 1024 * 256;
  tw.W[7] = W_O;   tw.T[7] = WT4;
  prep<<<8192 + 2464, 256, 0, stream>>>(x, xb, tw);

  gemm_bt<true><<<dim3(64, 5),  256, 0, stream>>>(xb, 1024, WT1, 1024, C1, 544, 544, 1024);
  gemm_mid<<<dim3(64, 28),      256, 0, stream>>>(C1, WT2, WT3, C2, C3, Vt);
  rope_qk<<<8704, 256, 0, stream>>>(C2, C1, Krr);
  flash_attn<<<dim3(64, 16), 256, 0, stream>>>(C2, C3, Krr, Vt, Oa);
  gemm_bt<false><<<dim3(64, 8), 256, 0, stream>>>(Oa, 1024, WT4, 1024, d_out, 1024, 1024, 1024);
}

// Round 12
// 269.498 us; speedup vs baseline: 1.9213x; 1.0021x over previous
//
#include <hip/hip_runtime.h>
#include <hip/hip_bf16.h>

// MLA forward, MI355X/gfx950.
// B=4, S=2048, D_MODEL=1024, H=16, D_H=64, D_HR=32, D_LATENT=256, d_qk=96.
//
// R12 = R11 (270.1us) + Qr-rope moved into flash_attn's PROLOGUE:
//  * rope pairs (2i,2i+1) are adjacent elements inside each lane's Qr bf16x8
//    fragment (kc0 = (c-4)*16 + h*8 is even) -> 4 complete pairs per fragment,
//    zero shuffles, ~50 VALU ops once per block. Trig state dies before the
//    K-loop (R10's regalloc poison was trig forced LIVE ACROSS the loop; a
//    prologue consume-immediately pattern has no such liveness).
//  * rope_qk shrinks to Kr-only (512 blocks) and runs right after gemm_dq
//    (only needs C1), off flash's critical path.
// flash main loop / epilogue untouched (R4/R6/R9 structure).

typedef __attribute__((ext_vector_type(8))) __bf16 bf16x8;
typedef __attribute__((ext_vector_type(4))) float f32x4;
typedef __attribute__((ext_vector_type(16))) float f32x16;
typedef __attribute__((ext_vector_type(4))) unsigned short us4;

#define DEV static __device__ __forceinline__

DEV unsigned short f2b(float f) {
  union { __hip_bfloat16 h; unsigned short u; } v;
  v.h = __float2bfloat16(f);
  return v.u;
}
DEV float b2f(unsigned short u) {
  union { unsigned short u; __hip_bfloat16 h; } v;
  v.u = u;
  return __bfloat162float(v.h);
}
DEV unsigned int f2b2(float lo, float hi) {   // packed 2xf32 -> 2xbf16
  union { __hip_bfloat162 h2; unsigned int u; } v;
  float2 t; t.x = lo; t.y = hi;
  v.h2 = __float22bfloat162_rn(t);
  return v.u;
}
DEV f32x4 mfma16(bf16x8 a, bf16x8 b, f32x4 c) {
  return __builtin_amdgcn_mfma_f32_16x16x32_bf16(a, b, c, 0, 0, 0);
}
DEV f32x16 mfma32(bf16x8 a, bf16x8 b, f32x16 c) {
  return __builtin_amdgcn_mfma_f32_32x32x16_bf16(a, b, c, 0, 0, 0);
}
DEV void load_lds16(const void* g, void* lds) {
  __builtin_amdgcn_global_load_lds((__attribute__((address_space(1))) void*)g,
                                   (__attribute__((address_space(3))) void*)lds,
                                   16, 0, 0);
}

// Q-side prescale folded into W_UQ^T / W_QR^T: (1/sqrt(96)) * log2(e).
#define KSC2f 0.14724444690f
// Clip bound in the scaled domain: 80 * KSC2.
#define CLIPf 11.7795557220f
// log2(10000)/16, RoPE inv-freq in exp2 form.
#define RINVf 0.8304820237686285f

// ---------------- prep: convert x (fp32->bf16) + 8 weight transposes, ONE dispatch ----------
struct TWArgs { const float* W[8]; unsigned short* T[8]; };
__global__ __launch_bounds__(256) void prep(const float* __restrict__ x,
                                            unsigned short* __restrict__ xb, TWArgs a) {
  if (blockIdx.x < 8192) {
    long i = (long)(blockIdx.x * 256 + threadIdx.x) * 4;
    float4 v = *(const float4*)(x + i);
    us4 o = { f2b(v.x), f2b(v.y), f2b(v.z), f2b(v.w) };
    *(us4*)(xb + i) = o;
    return;
  }
  int bid = blockIdx.x - 8192;
  int g;
  if      (bid < 256)  g = 0;
  else if (bid < 512)  g = 1;
  else if (bid < 544)  g = 2;
  else if (bid < 800)  g = 3;
  else if (bid < 928)  g = 4;
  else if (bid < 1184) g = 5;
  else if (bid < 1440) g = 6;
  else                 g = 7;
  const int starts[8] = {0, 256, 512, 544, 800, 928, 1184, 1440};
  int local = bid - starts[g];
  int K = (g >= 3 && g <= 6) ? 256 : 1024;
  int N = (g < 2) ? 256 : (g == 2 ? 32 : (g == 4 ? 512 : 1024));
  int tilesX = N >> 5;
  int n0 = (local % tilesX) * 32, k0 = (local / tilesX) * 32;
  const float* W = a.W[g];
  unsigned short* WT = a.T[g];
  float sc = (g == 3 || g == 4) ? KSC2f : 1.0f;
  __shared__ float tile[32][33];
  int tx = threadIdx.x & 31, ty = threadIdx.x >> 5;
#pragma unroll
  for (int i = 0; i < 32; i += 8)
    tile[ty + i][tx] = W[(size_t)(k0 + ty + i) * N + n0 + tx];
  __syncthreads();
#pragma unroll
  for (int i = 0; i < 32; i += 8)
    WT[(size_t)(n0 + ty + i) * K + k0 + tx] = f2b(tile[tx][ty + i] * sc);
}

// ---------------- Kr RoPE only: C1 kr_raw -> Krr (512 blocks) ----------------
__global__ __launch_bounds__(256) void rope_kr(const unsigned short* __restrict__ C1,
                                               unsigned short* __restrict__ Krr) {
  int idx = blockIdx.x * 256 + threadIdx.x;   // 2^17 threads exact
  int i = idx & 15, s = (idx >> 4) & 2047, b = idx >> 15;
  long src = (long)(b * 2048 + s) * 544 + 512 + 2 * i;
  float x1 = b2f(C1[src]), x2 = b2f(C1[src + 1]);
  float inv = exp2f(-(float)i * RINVf);
  float ang = (float)s * inv;
  float c = cosf(ang), sn = sinf(ang);
  long dst = (long)(b * 2048 + s) * 32 + 2 * i;
  Krr[dst]     = f2b(x1 * c - x2 * sn);
  Krr[dst + 1] = f2b(x1 * sn + x2 * c);
}

// ---------------- GEMM: C(M x N) = A(M x K, lda) @ Bt(N x K, ldb)^T ----------------
template <bool OUT_BF16>
__global__ __launch_bounds__(256) void gemm_bt(const unsigned short* __restrict__ A, int lda,
                                               const unsigned short* __restrict__ Bt, int ldb,
                                               void* __restrict__ Cv, int ldc, int N, int K) {
  __shared__ __align__(16) unsigned short As[128 * 32];
  __shared__ __align__(16) unsigned short Bs[128 * 32];
  const int t = threadIdx.x;
  const int w = t >> 6, lane = t & 63, ln = lane & 15, quad = lane >> 4;
  const int wr = w >> 1, wc = w & 1;
  const int bm0 = blockIdx.x * 128, bn0 = blockIdx.y * 128;
  const int srow = t >> 2, scol = (t & 3) * 8;
  f32x4 zero = {0.f, 0.f, 0.f, 0.f};
  f32x4 acc[4][4];
#pragma unroll
  for (int i = 0; i < 4; ++i)
#pragma unroll
    for (int j = 0; j < 4; ++j) acc[i][j] = zero;

  for (int k0 = 0; k0 < K; k0 += 32) {
#pragma unroll
    for (int r = 0; r < 2; ++r) {
      load_lds16(A + (long)(bm0 + r * 64 + srow) * lda + k0 + scol, (char*)As + r * 4096 + w * 1024);
      int brow = bn0 + r * 64 + srow;
      if (brow > N - 1) brow = N - 1;  // clamp (garbage cols guarded at write)
      load_lds16(Bt + (long)brow * ldb + k0 + scol, (char*)Bs + r * 4096 + w * 1024);
    }
    __syncthreads();
    bf16x8 af[4], bf[4];
#pragma unroll
    for (int i = 0; i < 4; ++i)
      af[i] = *(const bf16x8*)(As + (wr * 64 + i * 16 + ln) * 32 + quad * 8);
#pragma unroll
    for (int j = 0; j < 4; ++j)
      bf[j] = *(const bf16x8*)(Bs + (wc * 64 + j * 16 + ln) * 32 + quad * 8);
#pragma unroll
    for (int i = 0; i < 4; ++i)
#pragma unroll
      for (int j = 0; j < 4; ++j) acc[i][j] = mfma16(af[i], bf[j], acc[i][j]);
    __syncthreads();
  }
#pragma unroll
  for (int i = 0; i < 4; ++i)
#pragma unroll
    for (int j = 0; j < 4; ++j)
#pragma unroll
      for (int r = 0; r < 4; ++r) {
        int row = bm0 + wr * 64 + i * 16 + quad * 4 + r;
        int col = bn0 + wc * 64 + j * 16 + ln;
        if (col < N) {
          if (OUT_BF16)
            ((unsigned short*)Cv)[(long)row * ldc + col] = f2b(acc[i][j][r]);
          else
            ((float*)Cv)[(long)row * ldc + col] = acc[i][j][r];
        }
      }
}

// ---------------- merged mid GEMM (trig-free): Q up-proj AND KV up-proj ----------------
// grid (64, 28), all K=256, PLAIN epilogues only (R10 lesson: no trig here).
//  y in [0,12):  C2 = c_q @ WT2^T, row-major (Qr left RAW; flash ropes at load)
//  y in [12,20): C3 = c_kv @ W_UK^T, row-major
//  y in [20,28): V  = c_kv @ W_UV^T, transposed packed -> Vt[bh*64+d][s]
__global__ __launch_bounds__(256) void gemm_mid(const unsigned short* __restrict__ C1,
                                                const unsigned short* __restrict__ WT2,
                                                const unsigned short* __restrict__ WT3,
                                                unsigned short* __restrict__ C2,
                                                unsigned short* __restrict__ C3,
                                                unsigned short* __restrict__ Vt) {
  __shared__ __align__(16) unsigned short As[128 * 32];
  __shared__ __align__(16) unsigned short Bs[128 * 32];
  const int t = threadIdx.x;
  const int w = t >> 6, lane = t & 63, ln = lane & 15, quad = lane >> 4;
  const int wr = w >> 1, wc = w & 1;
  const int y = blockIdx.y;
  const unsigned short* A;
  const unsigned short* Bt;
  int bn0;
  if (y < 12)      { A = C1;       Bt = WT2;                       bn0 = y * 128; }
  else if (y < 20) { A = C1 + 256; Bt = WT3;                       bn0 = (y - 12) * 128; }
  else             { A = C1 + 256; Bt = WT3 + (size_t)1024 * 256;  bn0 = (y - 20) * 128; }
  const int bm0 = blockIdx.x * 128;
  const int srow = t >> 2, scol = (t & 3) * 8;
  f32x4 zero = {0.f, 0.f, 0.f, 0.f};
  f32x4 acc[4][4];
#pragma unroll
  for (int i = 0; i < 4; ++i)
#pragma unroll
    for (int j = 0; j < 4; ++j) acc[i][j] = zero;

  for (int k0 = 0; k0 < 256; k0 += 32) {
#pragma unroll
    for (int r = 0; r < 2; ++r) {
      load_lds16(A + (long)(bm0 + r * 64 + srow) * 544 + k0 + scol, (char*)As + r * 4096 + w * 1024);
      load_lds16(Bt + (long)(bn0 + r * 64 + srow) * 256 + k0 + scol, (char*)Bs + r * 4096 + w * 1024);
    }
    __syncthreads();
    bf16x8 af[4], bf[4];
#pragma unroll
    for (int i = 0; i < 4; ++i)
      af[i] = *(const bf16x8*)(As + (wr * 64 + i * 16 + ln) * 32 + quad * 8);
#pragma unroll
    for (int j = 0; j < 4; ++j)
      bf[j] = *(const bf16x8*)(Bs + (wc * 64 + j * 16 + ln) * 32 + quad * 8);
#pragma unroll
    for (int i = 0; i < 4; ++i)
#pragma unroll
      for (int j = 0; j < 4; ++j) acc[i][j] = mfma16(af[i], bf[j], acc[i][j]);
    __syncthreads();
  }

  if (y < 12) {
#pragma unroll
    for (int i = 0; i < 4; ++i)
#pragma unroll
      for (int j = 0; j < 4; ++j)
#pragma unroll
        for (int r = 0; r < 4; ++r) {
          int row = bm0 + wr * 64 + i * 16 + quad * 4 + r;
          int col = bn0 + wc * 64 + j * 16 + ln;
          C2[(long)row * 1536 + col] = f2b(acc[i][j][r]);
        }
  } else if (y < 20) {
#pragma unroll
    for (int i = 0; i < 4; ++i)
#pragma unroll
      for (int j = 0; j < 4; ++j)
#pragma unroll
        for (int r = 0; r < 4; ++r) {
          int row = bm0 + wr * 64 + i * 16 + quad * 4 + r;
          int col = bn0 + wc * 64 + j * 16 + ln;
          C3[(long)row * 1024 + col] = f2b(acc[i][j][r]);
        }
  } else {
#pragma unroll
    for (int i = 0; i < 4; ++i)
#pragma unroll
      for (int j = 0; j < 4; ++j) {
        int col = bn0 + wc * 64 + j * 16 + ln;          // 0..1023 = h*64+d
        int row0 = bm0 + wr * 64 + i * 16 + quad * 4;   // 4 consecutive seq rows, same b
        int b = row0 >> 11, sl = row0 & 2047;
        us4 pk = { f2b(acc[i][j][0]), f2b(acc[i][j][1]), f2b(acc[i][j][2]), f2b(acc[i][j][3]) };
        *(us4*)(Vt + ((size_t)(b * 16) * 64 + col) * 2048 + sl) = pk;
      }
  }
}

// ---------------- Flash attention: R4 structure + prologue Qr-rope ----------
//  * main loop / epilogue IDENTICAL to the 95.5-97.9us R4/R6/R9 kernel
//  * prologue ropes qf[4],qf[5] in-register: pairs are intra-lane (kc0 even),
//    4 pairs/fragment, trig consumed immediately (no cross-loop liveness)
//  * qi = 15 - blockIdx.y, post-barrier kr loads, ^(r&7)^(r>>3) swizzle,
//    KSC2 prescale, ones-MFMA row sums, __launch_bounds__(256,3)
__global__ __launch_bounds__(256, 3) void flash_attn(const unsigned short* __restrict__ C2,
                                                     const unsigned short* __restrict__ C3,
                                                     const unsigned short* __restrict__ Krr,
                                                     const unsigned short* __restrict__ Vt,
                                                     unsigned short* __restrict__ Oa) {
  __shared__ __align__(16) unsigned short Ks[2][4096];  // 64 keys(pi-staged) x 64 d, swizzled
  __shared__ __align__(16) unsigned short Vs[2][4096];  // 64 d x 64 keys(natural), swizzled

  const int tid = threadIdx.x;
  const int w = tid >> 6, lane = tid & 63;
  const int l31 = lane & 31, h = lane >> 5;
  const int bh = blockIdx.x, b = bh >> 4, head = bh & 15;
  const int bS = b * 2048;
  const int qi = 15 - (int)blockIdx.y;
  const int qb = qi * 128 + w * 32;
  const int nkt = 2 * qi + 2;
  const int q = qb + l31;               // this lane's q row
  const int pr = (l31 & ~12) | ((l31 & 4) << 1) | ((l31 & 8) >> 1);  // pi(l31)

  // Q B-operand fragments (pre-scaled by KSC2): per lane row q, 8 d's at h*8.
  const unsigned short* qp = C2 + (size_t)(bS + q) * 1536;
  bf16x8 qf[6];
#pragma unroll
  for (int c = 0; c < 4; ++c)
    qf[c] = *(const bf16x8*)(qp + head * 64 + c * 16 + h * 8);
#pragma unroll
  for (int c = 4; c < 6; ++c)
    qf[c] = *(const bf16x8*)(qp + 1024 + head * 32 + (c - 4) * 16 + h * 8);

  // Prologue Qr-rope: 4 intra-lane pairs per fragment; trig dead before the loop.
#pragma unroll
  for (int c = 4; c < 6; ++c) {
    union { bf16x8 v; unsigned short u[8]; } f;
    f.v = qf[c];
    const int i0 = ((c - 4) * 16 + h * 8) >> 1;   // first rope-pair index (0..15)
    union { unsigned int u[4]; bf16x8 v; } pk;
#pragma unroll
    for (int j = 0; j < 4; ++j) {
      float inv = exp2f(-(float)(i0 + j) * RINVf);
      float ang = (float)q * inv;
      float cc = cosf(ang), ss = sinf(ang);
      float x1 = b2f(f.u[2 * j]), x2 = b2f(f.u[2 * j + 1]);
      pk.u[j] = f2b2(fmaf(x1, cc, -(x2 * ss)), fmaf(x1, ss, x2 * cc));
    }
    qf[c] = pk.v;
  }

  // ones B-operand for row-sum MFMA
  union { unsigned short u[8]; bf16x8 v; } onesu;
#pragma unroll
  for (int i = 0; i < 8; ++i) onesu.u[i] = 0x3F80;  // bf16 1.0
  const bf16x8 ones = onesu.v;

  f32x16 o0 = {}, o1 = {}, osum = {};

  auto stage = [&](int buf, int key0) {
#pragma unroll
    for (int t = w; t < 8; t += 4) {   // K: dest row r <- source key key0+pi(r)
      int ci = t * 64 + lane;
      int r = ci >> 3, sl = ci & 7;
      int srcc = sl ^ (r & 7) ^ (r >> 3);
      int srck = (r & ~12) | ((r & 4) << 1) | ((r & 8) >> 1);
      load_lds16(C3 + (size_t)(bS + key0 + srck) * 1024 + head * 64 + srcc * 8,
                 &Ks[buf][t * 512]);
    }
#pragma unroll
    for (int t = w; t < 8; t += 4) {   // V^T: natural key order
      int ci = t * 64 + lane;
      int r = ci >> 3, sl = ci & 7;
      int srcc = sl ^ (r & 7) ^ (r >> 3);
      load_lds16(Vt + (size_t)((size_t)bh * 64 + r) * 2048 + key0 + srcc * 8,
                 &Vs[buf][t * 512]);
    }
  };

  stage(0, 0);
  for (int kt = 0; kt < nkt; ++kt) {
    __syncthreads();                    // drains vmcnt(0): stage(kt) visible
    const int c0 = kt * 64;
    const bool live = (c0 <= qb + 31);
    bf16x8 kr[4];                       // Kr A-frags from global (pi rows), BEFORE next stage
    if (live) {
#pragma unroll
      for (int m = 0; m < 2; ++m)
#pragma unroll
        for (int c = 0; c < 2; ++c)
          kr[m * 2 + c] = *(const bf16x8*)(Krr + (size_t)(bS + c0 + m * 32 + pr) * 32 +
                                           c * 16 + h * 8);
    }
    if (kt + 1 < nkt) stage((kt + 1) & 1, c0 + 64);
    if (!live) continue;

    const unsigned short* Kp = Ks[kt & 1];
    const unsigned short* Vp = Vs[kt & 1];

#pragma unroll
    for (int m = 0; m < 2; ++m) {
      if (c0 + m * 32 > qb + 31) continue;   // m-tile fully masked for this wave
      const int r = m * 32 + l31;            // staged K row this lane reads
      f32x16 s = {};
#pragma unroll
      for (int c = 0; c < 4; ++c) {
        int slot = (2 * c + h) ^ (r & 7) ^ (r >> 3);
        bf16x8 kf = *(const bf16x8*)(Kp + r * 64 + slot * 8);
        s = mfma32(kf, qf[c], s);
      }
      s = mfma32(kr[m * 2 + 0], qf[4], s);
      s = mfma32(kr[m * 2 + 1], qf[5], s);

      // exp in-register; actual key of reg p = c0+m*32+(p&3)+4*((p>>2)&1)+8h+16*(p>>3)
      const bool nm = (c0 + m * 32 + 31) > qb;   // touches diagonal for this wave
      float ev[16];
#pragma unroll
      for (int p = 0; p < 16; ++p) {
        float z = __builtin_amdgcn_fmed3f(s[p], -CLIPf, CLIPf);  // clip (scaled domain)
        if (nm) {
          int key = c0 + m * 32 + (p & 3) + 4 * ((p >> 2) & 1) + 8 * h + 16 * (p >> 3);
          if (key > q) z = -1e30f;
        }
        ev[p] = exp2f(z);
      }
      bf16x8 pf[2];
#pragma unroll
      for (int t = 0; t < 2; ++t) {
        union { unsigned int u[4]; bf16x8 v; } pk;
#pragma unroll
        for (int j = 0; j < 4; ++j)
          pk.u[j] = f2b2(ev[t * 8 + 2 * j], ev[t * 8 + 2 * j + 1]);
        pf[t] = pk.v;
      }
      // PV: A = pf (keys natural order by pi-identity), B = V fragments from Vs.
      // Row sums ride the MFMA pipe: osum += P @ ones.
#pragma unroll
      for (int t = 0; t < 2; ++t) {
        int tk = m * 2 + t;
        osum = mfma32(pf[t], ones, osum);
#pragma unroll
        for (int n = 0; n < 2; ++n) {
          int rr = n * 32 + l31;
          int slot = (2 * tk + h) ^ (rr & 7) ^ (rr >> 3);
          bf16x8 vf = *(const bf16x8*)(Vp + rr * 64 + slot * 8);
          if (n == 0) o0 = mfma32(pf[t], vf, o0);
          else        o1 = mfma32(pf[t], vf, o1);
        }
      }
    }
  }

  // ---- epilogue: osum[p] is the full row sum for row qrow; no exchange needed ----
#pragma unroll
  for (int p = 0; p < 16; ++p) {
    int qrow = (p & 3) + 8 * (p >> 2) + 4 * h;  // o C-layout row
    float rl = 1.0f / osum[p];
    size_t base = (size_t)(bS + qb + qrow) * 1024 + head * 64;
    Oa[base + l31]      = f2b(o0[p] * rl);
    Oa[base + 32 + l31] = f2b(o1[p] * rl);
  }
}

// ---------------- launcher ----------------
extern "C" void kernel_launch(void* const* d_in, const int* in_sizes, int n_in,
                              void* d_out, int out_size, void* d_ws, size_t ws_size,
                              hipStream_t stream) {
  (void)in_sizes; (void)n_in; (void)out_size; (void)ws_size;
  const float* x     = (const float*)d_in[0];
  const float* W_DQ  = (const float*)d_in[1];
  const float* W_UQ  = (const float*)d_in[2];
  const float* W_QR  = (const float*)d_in[3];
  const float* W_DKV = (const float*)d_in[4];
  const float* W_UK  = (const float*)d_in[5];
  const float* W_UV  = (const float*)d_in[6];
  const float* W_KR  = (const float*)d_in[7];
  const float* W_O   = (const float*)d_in[8];

  char* p = (char*)d_ws;
  unsigned short* xb  = (unsigned short*)p; p += (size_t)8192 * 1024 * 2;
  unsigned short* WT1 = (unsigned short*)p; p += (size_t)544 * 1024 * 2;   // [W_DQ^T; W_DKV^T; W_KR^T]
  unsigned short* WT2 = (unsigned short*)p; p += (size_t)1536 * 256 * 2;   // [W_UQ^T; W_QR^T] (KSC2-scaled)
  unsigned short* WT3 = (unsigned short*)p; p += (size_t)2048 * 256 * 2;   // [W_UK^T; W_UV^T]
  unsigned short* WT4 = (unsigned short*)p; p += (size_t)1024 * 1024 * 2;  // W_O^T
  unsigned short* C1  = (unsigned short*)p; p += (size_t)8192 * 544 * 2;   // [c_q | c_kv | kr_raw]
  unsigned short* C2  = (unsigned short*)p; p += (size_t)8192 * 1536 * 2;  // [Qc | Qr RAW (flash ropes)]
  unsigned short* C3  = (unsigned short*)p; p += (size_t)8192 * 1024 * 2;  // Kc only
  unsigned short* Krr = (unsigned short*)p; p += (size_t)8192 * 32 * 2;    // roped Kr
  unsigned short* Vt  = (unsigned short*)p; p += (size_t)64 * 64 * 2048 * 2;
  unsigned short* Oa  = (unsigned short*)p; p += (size_t)8192 * 1024 * 2;  // attn out (B,S,1024)

  TWArgs tw;
  tw.W[0] = W_DQ;  tw.T[0] = WT1;
  tw.W[1] = W_DKV; tw.T[1] = WT1 + 256 * 1024;
  tw.W[2] = W_KR;  tw.T[2] = WT1 + 512 * 1024;
  tw.W[3] = W_UQ;  tw.T[3] = WT2;
  tw.W[4] = W_QR;  tw.T[4] = WT2 + 1024 * 256;
  tw.W[5] = W_UK;  tw.T[5] = WT3;
  tw.W[6] = W_UV;  tw.T[6] = WT3 + 1024 * 256;
  tw.W[7] = W_O;   tw.T[7] = WT4;
  prep<<<8192 + 2464, 256, 0, stream>>>(x, xb, tw);

  gemm_bt<true><<<dim3(64, 5),  256, 0, stream>>>(xb, 1024, WT1, 1024, C1, 544, 544, 1024);
  rope_kr<<<512, 256, 0, stream>>>(C1, Krr);            // only needs C1; off flash's critical path
  gemm_mid<<<dim3(64, 28),      256, 0, stream>>>(C1, WT2, WT3, C2, C3, Vt);
  flash_attn<<<dim3(64, 16), 256, 0, stream>>>(C2, C3, Krr, Vt, Oa);
  gemm_bt<false><<<dim3(64, 8), 256, 0, stream>>>(Oa, 1024, WT4, 1024, d_out, 1024, 1024, 1024);
}